// Round 1
// baseline (198.768 us; speedup 1.0000x reference)
//
#include <hip/hip_runtime.h>
#include <hip/hip_bf16.h>
#include <cstdint>

#define B_ 4
#define H_ 80
#define W_ 80
#define CH_ 256
#define NC_ 22
#define DIM_ 256
#define NPIX (B_*H_*W_)

typedef unsigned short ushort;
typedef __attribute__((ext_vector_type(8))) short short8;     // 8 bf16 = 4 VGPR
typedef __attribute__((ext_vector_type(4))) float floatx4;    // MFMA C/D frag

static __device__ inline ushort f2bf(float v) {
    __hip_bfloat16 h = __float2bfloat16(v);   // RNE
    ushort r;
    __builtin_memcpy(&r, &h, 2);
    return r;
}
static __device__ inline unsigned pk2(float a, float b) {
    return (unsigned)f2bf(a) | ((unsigned)f2bf(b) << 16);
}

// ---------------------------------------------------------------------------
// prep: fused {sel (raw, (m,k)-parallel)} + {weight repack}.
// blocks [0,900): sel. thread t = k*NPIX + m. Writes RAW sel (no norm).
// blocks [900,972): cvt_w LDS transpose cw[c][k][d] f32 -> wbT[k][d][c] bf16.
// ---------------------------------------------------------------------------
__global__ __launch_bounds__(256) void prep(const float* __restrict__ seg,
                                            const float* __restrict__ cw,
                                            float* __restrict__ ssel,
                                            ushort* __restrict__ wbT)
{
    __shared__ ushort ls[32][260];
    if (blockIdx.x < 900) {
        const int t = blockIdx.x * 256 + threadIdx.x;     // = k*NPIX + m
        const int k = t / NPIX;
        const int m = t - k * NPIX;
        const int w = m % W_;
        const int h = (m / W_) % H_;
        const int b = m / (W_ * H_);

        const float2* c2 = (const float2*)(seg + (size_t)m * NC_);
        float cv[NC_];
        #pragma unroll
        for (int c = 0; c < NC_ / 2; ++c) { float2 v = c2[c]; cv[2*c] = v.x; cv[2*c+1] = v.y; }
        float mx = -1e30f;
        #pragma unroll
        for (int c = 0; c < NC_; ++c) mx = fmaxf(mx, cv[c]);

        const int i = k / 3, j = k % 3;
        const int hh = h + i - 1, ww = w + j - 1;
        float s = 0.f;
        if (hh >= 0 && hh < H_ && ww >= 0 && ww < W_) {
            const float2* n2 = (const float2*)(seg + ((size_t)((b * H_ + hh) * W_ + ww)) * NC_);
            #pragma unroll
            for (int c = 0; c < NC_ / 2; ++c) {
                float2 v = n2[c];
                s += (cv[2*c]   == mx) ? v.x : 0.f;
                s += (cv[2*c+1] == mx) ? v.y : 0.f;
            }
        }
        ssel[t] = s;                                      // raw sel
    } else {
        const int bx = blockIdx.x - 900;
        const int k  = bx / 8;
        const int c0 = (bx % 8) * 32;
        const int c   = threadIdx.x >> 3;                 // 0..31
        const int seg8 = threadIdx.x & 7;                 // 0..7

        const float* src = cw + ((size_t)(c0 + c) * 9 + k) * DIM_ + seg8 * 32;
        #pragma unroll
        for (int e = 0; e < 32; e += 4) {
            float4 v = *(const float4*)(src + e);
            unsigned* dst = (unsigned*)&ls[c][seg8 * 32 + e];
            dst[0] = pk2(v.x, v.y);
            dst[1] = pk2(v.z, v.w);
        }
        __syncthreads();

        const int d = threadIdx.x;                        // 0..255
        ushort tmp[32];
        #pragma unroll
        for (int cc = 0; cc < 32; ++cc) tmp[cc] = ls[cc][d];
        uint4 o[4];
        __builtin_memcpy(o, tmp, 64);
        uint4* dst = (uint4*)(wbT + ((size_t)k * 256 + d) * 256 + c0);
        dst[0] = o[0]; dst[1] = o[1]; dst[2] = o[2]; dst[3] = o[3];
    }
}

// ---------------------------------------------------------------------------
// conv2: taps-outer implicit GEMM, scale folded into bf16 staging (single
// rounding of s*x in f32 -> exact-quality numerics, no P accumulator).
// Block = row (M=80 padded to 96) x 128 d. Waves: 2 wm (48 rows) x 2 wn (64 d),
// jn=4 frags/wave -> each A b128 read feeds 4 MFMAs. Rows 80..95 alias a
// zeroed 16-row LDS region. B reg-ring prefetched one kk ahead (slot=kk&1).
// One barrier per interval; staging issued mid-interval (after kk0).
// ---------------------------------------------------------------------------
__global__ __launch_bounds__(256, 3) void conv2(const float* __restrict__ x,
                                                const float* __restrict__ sraw,
                                                const ushort* __restrict__ wbT,
                                                float* __restrict__ out)
{
    __shared__ ushort xsA[2][80 * 136];      // 43.5 KB
    __shared__ ushort zs[16 * 136];          // 4.25 KB zero rows 80..95
    __shared__ float  sl[9][80];             // 2.8 KB (sel*norm, f32)

    const int tid  = threadIdx.x;
    const int lane = tid & 63;
    const int wv   = tid >> 6;
    const int wm   = wv >> 1;                // row half: 0 -> rows 0..47, 1 -> 48..95
    const int wn   = wv & 1;                 // d half: wn*64
    const int ln   = lane & 15;
    const int quad = lane >> 4;
    const int rt   = blockIdx.x;             // b*H + h
    const int b    = rt / H_;
    const int h    = rt % H_;
    const int d0   = blockIdx.y * 128;

    // zero the phantom-row region
    for (int t2 = tid; t2 < 16 * 136 / 2; t2 += 256) ((unsigned*)zs)[t2] = 0u;

    // sl = raw_sel * norm (norm folded here; raw sel from prep)
    if (tid < 80) {
        float raw[9]; int cnt = 0;
        #pragma unroll
        for (int k = 0; k < 9; ++k) {
            raw[k] = sraw[k * NPIX + rt * W_ + tid];
            cnt += (raw[k] != 0.f) ? 1 : 0;
        }
        const float norm = (cnt > 0) ? 9.f / (float)cnt : 0.f;
        #pragma unroll
        for (int k = 0; k < 9; ++k) sl[k][tid] = raw[k] * norm;
    }
    __syncthreads();                          // sl ready for stage(0)

    // per-thread B base offset (ushort units)
    const int Dbase = (d0 + wn * 64 + ln) * 256 + quad * 8;

    floatx4 O[3][4];
    #pragma unroll
    for (int im = 0; im < 3; ++im)
        #pragma unroll
        for (int jn = 0; jn < 4; ++jn)
            O[im][jn] = (floatx4){0.f, 0.f, 0.f, 0.f};

    short8 rg[2][4];                          // B ring, slot = kk&1 (static)

    auto loadBn = [&](int itn, int kkn, int slot) {
        const int ii  = itn / 6;
        const int rem = itn % 6;
        const int ccn = (rem / 3) * 128;
        const int jjn = rem % 3;
        const int kn  = 3 * ii + jjn;
        const ushort* bb = wbT + (size_t)kn * 65536 + Dbase + ccn + kkn * 32;
        #pragma unroll
        for (int jn = 0; jn < 4; ++jn)
            rg[slot][jn] = *(const short8*)(bb + jn * 4096);
    };

    // stage tile for interval nit: bf16(s_k[m] * x) with f32 multiply (single round)
    auto stage = [&](int nit) {
        const int ii  = nit / 6;
        const int rem = nit % 6;
        const int ccn = (rem / 3) * 128;
        const int jjn = rem % 3;
        const int kn  = 3 * ii + jjn;
        const int rr  = h + ii - 1;
        const bool rowok = (rr >= 0) && (rr < H_);
        ushort* wr = xsA[nit & 1];
        const float* xrow = x + ((size_t)((b * H_ + (rowok ? rr : 0)) * W_)) * CH_ + ccn;
        #pragma unroll
        for (int r = 0; r < 5; ++r) {
            const int q  = tid + 256 * r;
            const int qm = q >> 4;            // output pixel / LDS row 0..79
            const int qc = q & 15;            // 16B chunk in 128-ch half
            const int col = qm + jjn - 1;
            const bool v = rowok && (col >= 0) && (col < W_);
            uint4 o = make_uint4(0u, 0u, 0u, 0u);
            if (v) {
                const float s = sl[kn][qm];
                const float* f = xrow + (size_t)col * CH_ + qc * 8;
                float4 A  = *(const float4*)f;
                float4 Bv = *(const float4*)(f + 4);
                o = make_uint4(pk2(s * A.x, s * A.y), pk2(s * A.z, s * A.w),
                               pk2(s * Bv.x, s * Bv.y), pk2(s * Bv.z, s * Bv.w));
            }
            *(uint4*)&wr[qm * 136 + qc * 8] = o;
        }
    };

    // prologue: stage interval 0, preload B(0,0)
    stage(0);
    loadBn(0, 0, 0);
    __syncthreads();

    for (int it = 0; it < 18; ++it) {
        const ushort* bp = xsA[it & 1];
        const ushort* aps[3];
        #pragma unroll
        for (int im = 0; im < 3; ++im) {
            const int row = wm * 48 + im * 16 + ln;
            aps[im] = ((row < 80) ? (bp + row * 136) : (zs + (row - 80) * 136)) + quad * 8;
        }

        // kk = 0 (uses slot 0; prefetch kk1 -> slot 1)
        loadBn(it, 1, 1);
        {
            short8 a[3];
            #pragma unroll
            for (int im = 0; im < 3; ++im) a[im] = *(const short8*)(aps[im] + 0 * 32);
            #pragma unroll
            for (int im = 0; im < 3; ++im)
                #pragma unroll
                for (int jn = 0; jn < 4; ++jn)
                    O[im][jn] = __builtin_amdgcn_mfma_f32_16x16x32_bf16(a[im], rg[0][jn], O[im][jn], 0, 0, 0);
        }

        if (it < 17) stage(it + 1);           // globals+pack+ds_write overlap kk1..3

        // kk = 1 (slot 1; prefetch kk2 -> slot 0)
        loadBn(it, 2, 0);
        {
            short8 a[3];
            #pragma unroll
            for (int im = 0; im < 3; ++im) a[im] = *(const short8*)(aps[im] + 1 * 32);
            #pragma unroll
            for (int im = 0; im < 3; ++im)
                #pragma unroll
                for (int jn = 0; jn < 4; ++jn)
                    O[im][jn] = __builtin_amdgcn_mfma_f32_16x16x32_bf16(a[im], rg[1][jn], O[im][jn], 0, 0, 0);
        }

        // kk = 2 (slot 0; prefetch kk3 -> slot 1)
        loadBn(it, 3, 1);
        {
            short8 a[3];
            #pragma unroll
            for (int im = 0; im < 3; ++im) a[im] = *(const short8*)(aps[im] + 2 * 32);
            #pragma unroll
            for (int im = 0; im < 3; ++im)
                #pragma unroll
                for (int jn = 0; jn < 4; ++jn)
                    O[im][jn] = __builtin_amdgcn_mfma_f32_16x16x32_bf16(a[im], rg[0][jn], O[im][jn], 0, 0, 0);
        }

        // kk = 3 (slot 1; prefetch next interval kk0 -> slot 0)
        if (it < 17) loadBn(it + 1, 0, 0);
        {
            short8 a[3];
            #pragma unroll
            for (int im = 0; im < 3; ++im) a[im] = *(const short8*)(aps[im] + 3 * 32);
            #pragma unroll
            for (int im = 0; im < 3; ++im)
                #pragma unroll
                for (int jn = 0; jn < 4; ++jn)
                    O[im][jn] = __builtin_amdgcn_mfma_f32_16x16x32_bf16(a[im], rg[1][jn], O[im][jn], 0, 0, 0);
        }

        __syncthreads();
    }

    // epilogue: C/D layout col(d)=lane&15, row(m)=quad*4+reg; skip phantom rows
    #pragma unroll
    for (int im = 0; im < 3; ++im) {
        if (!(wm == 1 && im == 2)) {
            #pragma unroll
            for (int jn = 0; jn < 4; ++jn) {
                const int dd = d0 + wn * 64 + jn * 16 + ln;
                #pragma unroll
                for (int r = 0; r < 4; ++r) {
                    const int m = wm * 48 + im * 16 + quad * 4 + r;
                    out[((size_t)(rt * W_ + m)) * DIM_ + dd] = O[im][jn][r];
                }
            }
        }
    }
}

extern "C" void kernel_launch(void* const* d_in, const int* in_sizes, int n_in,
                              void* d_out, int out_size, void* d_ws, size_t ws_size,
                              hipStream_t stream)
{
    const float* x   = (const float*)d_in[0];   // (4,80,80,256) f32
    const float* seg = (const float*)d_in[1];   // (4,80,80,22)  f32
    const float* cw  = (const float*)d_in[2];   // (256,3,3,256) f32
    float* out = (float*)d_out;

    float*  ssel = (float*)d_ws;                             // 921600 B (raw sel)
    ushort* wbT  = (ushort*)((char*)d_ws + 921600);          // 1179648 B

    prep<<<dim3(900 + 72), dim3(256), 0, stream>>>(seg, cw, ssel, wbT);
    conv2<<<dim3(B_ * H_, 2), dim3(256), 0, stream>>>(x, ssel, wbT, out);
}